// Round 11
// baseline (372.099 us; speedup 1.0000x reference)
//
#include <hip/hip_runtime.h>
#include <hip/hip_bf16.h>

#define NN 50000
#define NE 800000

using bf16x8 = __attribute__((ext_vector_type(8))) short;
using f32x4  = __attribute__((ext_vector_type(4))) float;
using f32x2  = __attribute__((ext_vector_type(2))) float;

__device__ __forceinline__ ushort f2bf(float f) {
  uint x = __float_as_uint(f);
  return (ushort)((x + 0x7FFFu + ((x >> 16) & 1u)) >> 16);
}
__device__ __forceinline__ float bf2f(ushort u) {
  return __uint_as_float(((uint)u) << 16);
}
__device__ __forceinline__ float leaky(float x) { return fmaxf(x, 0.2f * x); }

// fp8 e4m3 (OCP) helpers — HW packed converts
__device__ __forceinline__ unsigned char f32_to_fp8(float v) {
  int pk = __builtin_amdgcn_cvt_pk_fp8_f32(v, v, 0, false);
  return (unsigned char)(pk & 0xff);
}
__device__ __forceinline__ float4 fp8x4_to_f32(uint u) {
  f32x2 lo = __builtin_amdgcn_cvt_pk_f32_fp8((int)u, false);
  f32x2 hi = __builtin_amdgcn_cvt_pk_f32_fp8((int)u, true);
  return make_float4(lo[0], lo[1], hi[0], hi[1]);
}

// async global->LDS, 16B per lane
__device__ __forceinline__ void gload_lds16(const void* g, void* l) {
  __builtin_amdgcn_global_load_lds(
      (const __attribute__((address_space(1))) unsigned int*)g,
      (__attribute__((address_space(3))) unsigned int*)l, 16, 0, 0);
}

// ---------------- CSR build ----------------

__global__ __launch_bounds__(256) void hist_kernel(const int* __restrict__ dst,
                                                   int* __restrict__ counts) {
  int e = blockIdx.x * 256 + threadIdx.x;
  if (e < NE) atomicAdd(&counts[dst[e]], 1);
}

__global__ __launch_bounds__(1024) void scan1_kernel(const int* __restrict__ counts,
                                                     int* __restrict__ partial,
                                                     int* __restrict__ blockSums) {
  __shared__ int sm[1024];
  int i = blockIdx.x * 1024 + threadIdx.x;
  sm[threadIdx.x] = (i < NN) ? counts[i] : 0;
  __syncthreads();
  for (int off = 1; off < 1024; off <<= 1) {
    int t = (threadIdx.x >= off) ? sm[threadIdx.x - off] : 0;
    __syncthreads();
    sm[threadIdx.x] += t;
    __syncthreads();
  }
  if (i < NN) partial[i] = sm[threadIdx.x];
  if (threadIdx.x == 1023) blockSums[blockIdx.x] = sm[1023];
}

__global__ __launch_bounds__(256) void scan23_kernel(const int* __restrict__ partial,
                                                     const int* __restrict__ blockSums,
                                                     int* __restrict__ rowPtr) {
  int i = blockIdx.x * 256 + threadIdx.x;
  if (i < NN) {
    const int nb = i >> 10;
    int off = 0;
    for (int b = 0; b < nb; ++b) off += blockSums[b];
    rowPtr[i + 1] = partial[i] + off;
    if (i == 0) rowPtr[0] = 0;
  }
}

__global__ __launch_bounds__(256) void fill_kernel(const int* __restrict__ srcArr,
                                                   const int* __restrict__ dstArr,
                                                   const int* __restrict__ rowPtr,
                                                   int* __restrict__ cursor,
                                                   int* __restrict__ colSrc) {
  int e = blockIdx.x * 256 + threadIdx.x;
  if (e < NE) {
    int d = dstArr[e];
    int p = rowPtr[d] + atomicAdd(&cursor[d], 1);
    colSrc[p] = srcArr[e];
  }
}

// ---------------- pre-fragment B' = [W | pad | W@att_s | W@att_d | pad] into MFMA lane order ----

__device__ __forceinline__ void prefrag_one(int idx, const float* __restrict__ W,
                                            const float* __restrict__ atS,
                                            const float* __restrict__ atD,
                                            ushort* __restrict__ Bf,
                                            int Mout, int Mpad, int nh, int Cdim, int KC) {
  const int i = idx & 7;
  const int lane = (idx >> 3) & 63;
  const int kc = (idx >> 9) % KC;
  const int ct = idx / (KC * 512);
  const int k = kc * 32 + (lane >> 4) * 8 + i;
  const int col = ct * 16 + (lane & 15);
  float v = 0.f;
  if (col < Mout) {
    v = W[(size_t)k * Mout + col];
  } else if (col >= Mpad && col < Mpad + nh) {
    const int h = col - Mpad; float s = 0.f;
    for (int c = 0; c < Cdim; ++c) s += W[(size_t)k * Mout + h * Cdim + c] * atS[h * Cdim + c];
    v = s;
  } else if (col >= Mpad + nh && col < Mpad + 2 * nh) {
    const int h = col - Mpad - nh; float s = 0.f;
    for (int c = 0; c < Cdim; ++c) s += W[(size_t)k * Mout + h * Cdim + c] * atD[h * Cdim + c];
    v = s;
  }
  Bf[idx] = f2bf(v);
}

#define T1 (17 * 4 * 512)
#define T2 (17 * 8 * 512)
#define T3 (5 * 8 * 512)

__global__ __launch_bounds__(256) void prefrag_all_kernel(
    const float* __restrict__ W1, const float* __restrict__ a1s, const float* __restrict__ a1d,
    const float* __restrict__ W2, const float* __restrict__ a2s, const float* __restrict__ a2d,
    const float* __restrict__ W3, const float* __restrict__ a3s, const float* __restrict__ a3d,
    ushort* __restrict__ Bf1, ushort* __restrict__ Bf2, ushort* __restrict__ Bf3) {
  int idx = blockIdx.x * 256 + threadIdx.x;
  if (idx < T1) {
    prefrag_one(idx, W1, a1s, a1d, Bf1, 256, 256, 4, 64, 4);
  } else if (idx < T1 + T2) {
    prefrag_one(idx - T1, W2, a2s, a2d, Bf2, 256, 256, 4, 64, 8);
  } else if (idx < T1 + T2 + T3) {
    prefrag_one(idx - T1 - T2, W3, a3s, a3d, Bf3, 40, 64, 1, 40, 8);
  }
}

// ---------------- bf16 MFMA GEMM: 128-row blocks (8 waves) x 2 column-groups ----------------
// gridDim.y = 2; group g covers CPG tiles starting at ct = g*STEP (overlap tile writes
// identical bytes twice — benign). LDS halves, VGPRs drop, 2x blocks -> latency hiding.

template <int CPG, int STEP, int KC, bool AF32, bool OUT8>
__global__ __launch_bounds__(512) void gemm_mfma_kernel(const void* __restrict__ Araw,
                                                        const ushort* __restrict__ Bf,
                                                        void* __restrict__ xwOut,
                                                        float* __restrict__ asB,
                                                        float* __restrict__ adB,
                                                        int Mpad, int nh) {
  __shared__ __align__(16) ushort sB[2][CPG * 512];
  constexpr int K = KC * 32;
  const int lane = threadIdx.x & 63;
  const int w = threadIdx.x >> 6;         // 8 waves
  const int ctBase = blockIdx.y * STEP;
  const int rowBase = blockIdx.x * 128 + w * 16;
  const int arow = min(rowBase + (lane & 15), NN - 1);   // clamp; no early return (barriers!)
  const int koff = (lane >> 4) * 8;
  f32x4 acc[CPG];
#pragma unroll
  for (int j = 0; j < CPG; ++j) acc[j] = (f32x4){0.f, 0.f, 0.f, 0.f};

#pragma unroll
  for (int j = 0; j < CPG; ++j) {
    if ((j & 7) == w)
      gload_lds16(Bf + (((size_t)(ctBase + j) * KC) << 9) + lane * 8, &sB[0][j * 512]);
  }
  __syncthreads();

#pragma unroll
  for (int kc = 0; kc < KC; ++kc) {
    const int nb = kc & 1;
    if (kc + 1 < KC) {
#pragma unroll
      for (int j = 0; j < CPG; ++j) {
        if ((j & 7) == w)
          gload_lds16(Bf + (((size_t)(ctBase + j) * KC + kc + 1) << 9) + lane * 8,
                      &sB[nb ^ 1][j * 512]);
      }
    }
    bf16x8 af;
    if constexpr (AF32) {
      const float* ap = (const float*)Araw + (size_t)arow * K + koff + kc * 32;
      float4 p0 = *(const float4*)ap;
      float4 p1 = *(const float4*)(ap + 4);
      af[0] = (short)f2bf(p0.x); af[1] = (short)f2bf(p0.y);
      af[2] = (short)f2bf(p0.z); af[3] = (short)f2bf(p0.w);
      af[4] = (short)f2bf(p1.x); af[5] = (short)f2bf(p1.y);
      af[6] = (short)f2bf(p1.z); af[7] = (short)f2bf(p1.w);
    } else {
      const ushort* ap = (const ushort*)Araw + (size_t)arow * K + koff + kc * 32;
      af = *reinterpret_cast<const bf16x8*>(ap);
    }
#pragma unroll
    for (int j = 0; j < CPG; ++j) {
      bf16x8 bfr = *reinterpret_cast<const bf16x8*>(&sB[nb][j * 512 + lane * 8]);
      acc[j] = __builtin_amdgcn_mfma_f32_16x16x32_bf16(af, bfr, acc[j], 0, 0, 0);
    }
    __syncthreads();   // drains vmcnt (prefetch DMA) + orders buffer reuse
  }

  const int colL = lane & 15;
  const int rquad = (lane >> 4) * 4;
#pragma unroll
  for (int j = 0; j < CPG; ++j) {
    const int col = (ctBase + j) * 16 + colL;
#pragma unroll
    for (int r = 0; r < 4; ++r) {
      const int row = rowBase + rquad + r;
      if (row < NN) {
        const float v = acc[j][r];
        if (col < Mpad) {
          if constexpr (OUT8) {
            ((unsigned char*)xwOut)[(size_t)row * Mpad + col] = f32_to_fp8(v);
          } else {
            ((ushort*)xwOut)[(size_t)row * Mpad + col] = f2bf(v);
          }
        } else if (col < Mpad + nh) {
          asB[(size_t)row * nh + (col - Mpad)] = v;
        } else if (col < Mpad + 2 * nh) {
          adB[(size_t)row * nh + (col - Mpad - nh)] = v;
        }
      }
    }
  }
}

// ---------------- aggregation: wave/node; fast single-pass softmax for deg<=64 ----------------

__global__ __launch_bounds__(256) void aggregate256_kernel(
    const unsigned char* __restrict__ xw, const float* __restrict__ asB,
    const float* __restrict__ adB,
    const int* __restrict__ rowPtr, const int* __restrict__ colSrc,
    const float* __restrict__ bias, ushort* __restrict__ hout, int applyElu) {
  __shared__ int   lsrc[4][64];    // row byte offsets (src*256)
  __shared__ float lw[4][256];
  const int n = (blockIdx.x * blockDim.x + threadIdx.x) >> 6;
  if (n >= NN) return;
  const int lane = threadIdx.x & 63;
  const int wv = (threadIdx.x >> 6) & 3;
  const int h = lane >> 4;
  const int ch = lane * 4;
  const int p0 = rowPtr[n], deg = rowPtr[n + 1] - p0;
  const float4 ad4 = *(const float4*)(adB + n * 4);
  const float4 as4 = *(const float4*)(asB + n * 4);
  float4 es;  // self-loop logit per head
  es.x = leaky(as4.x + ad4.x); es.y = leaky(as4.y + ad4.y);
  es.z = leaky(as4.z + ad4.z); es.w = leaky(as4.w + ad4.w);
  float4 s, acc;
  float4 m;

  if (deg <= 64) {
    // ---- fast path: one chunk, single-pass softmax ----
    const bool valid = lane < deg;
    const int src = valid ? colSrc[p0 + lane] : n;
    const float4 a4 = *(const float4*)(asB + src * 4);
    float4 ev;
    ev.x = valid ? leaky(a4.x + ad4.x) : -3.0e38f;
    ev.y = valid ? leaky(a4.y + ad4.y) : -3.0e38f;
    ev.z = valid ? leaky(a4.z + ad4.z) : -3.0e38f;
    ev.w = valid ? leaky(a4.w + ad4.w) : -3.0e38f;
    float4 mc = ev;
#pragma unroll
    for (int o = 1; o < 64; o <<= 1) {
      mc.x = fmaxf(mc.x, __shfl_xor(mc.x, o));
      mc.y = fmaxf(mc.y, __shfl_xor(mc.y, o));
      mc.z = fmaxf(mc.z, __shfl_xor(mc.z, o));
      mc.w = fmaxf(mc.w, __shfl_xor(mc.w, o));
    }
    m.x = fmaxf(es.x, mc.x); m.y = fmaxf(es.y, mc.y);
    m.z = fmaxf(es.z, mc.z); m.w = fmaxf(es.w, mc.w);
    float4 w4;
    w4.x = valid ? __expf(ev.x - m.x) : 0.f;
    w4.y = valid ? __expf(ev.y - m.y) : 0.f;
    w4.z = valid ? __expf(ev.z - m.z) : 0.f;
    w4.w = valid ? __expf(ev.w - m.w) : 0.f;
    lsrc[wv][lane] = src << 8;
    *(float4*)&lw[wv][lane * 4] = w4;
    float4 ss = w4;
#pragma unroll
    for (int o = 1; o < 64; o <<= 1) {
      ss.x += __shfl_xor(ss.x, o);
      ss.y += __shfl_xor(ss.y, o);
      ss.z += __shfl_xor(ss.z, o);
      ss.w += __shfl_xor(ss.w, o);
    }
    float4 wself;
    wself.x = __expf(es.x - m.x); wself.y = __expf(es.y - m.y);
    wself.z = __expf(es.z - m.z); wself.w = __expf(es.w - m.w);
    s.x = wself.x + ss.x; s.y = wself.y + ss.y;
    s.z = wself.z + ss.z; s.w = wself.w + ss.w;
    const float wsh = (h == 0) ? wself.x : (h == 1) ? wself.y : (h == 2) ? wself.z : wself.w;
    const float4 x4 = fp8x4_to_f32(*(const uint*)(xw + (size_t)n * 256 + ch));
    acc = make_float4(wsh * x4.x, wsh * x4.y, wsh * x4.z, wsh * x4.w);
    // weighted gather, unroll 4 (round up to 4; dummies have w=0)
    const int cdr = (deg + 3) & ~3;
    for (int j = 0; j < cdr; j += 4) {
      const int o0 = lsrc[wv][j + 0], o1 = lsrc[wv][j + 1];
      const int o2 = lsrc[wv][j + 2], o3 = lsrc[wv][j + 3];
      const float w0 = lw[wv][(j + 0) * 4 + h];
      const float w1 = lw[wv][(j + 1) * 4 + h];
      const float w2 = lw[wv][(j + 2) * 4 + h];
      const float w3 = lw[wv][(j + 3) * 4 + h];
      const uint u0 = *(const uint*)(xw + o0 + ch);
      const uint u1 = *(const uint*)(xw + o1 + ch);
      const uint u2 = *(const uint*)(xw + o2 + ch);
      const uint u3 = *(const uint*)(xw + o3 + ch);
      const float4 x0 = fp8x4_to_f32(u0), x1 = fp8x4_to_f32(u1);
      const float4 x2 = fp8x4_to_f32(u2), x3 = fp8x4_to_f32(u3);
      acc.x += w0 * x0.x + w1 * x1.x + w2 * x2.x + w3 * x3.x;
      acc.y += w0 * x0.y + w1 * x1.y + w2 * x2.y + w3 * x3.y;
      acc.z += w0 * x0.z + w1 * x1.z + w2 * x2.z + w3 * x3.z;
      acc.w += w0 * x0.w + w1 * x1.w + w2 * x2.w + w3 * x3.w;
    }
  } else {
    // ---- general path: online-softmax chunks ----
    m = es;
    s = make_float4(1.f, 1.f, 1.f, 1.f);
    const float4 x4 = fp8x4_to_f32(*(const uint*)(xw + (size_t)n * 256 + ch));
    acc = make_float4(x4.x, x4.y, x4.z, x4.w);
    for (int c0 = 0; c0 < deg; c0 += 64) {
      const int e = c0 + lane;
      const bool valid = e < deg;
      const int src = valid ? colSrc[p0 + e] : n;
      const float4 a4 = *(const float4*)(asB + src * 4);
      float4 ev;
      ev.x = valid ? leaky(a4.x + ad4.x) : -3.0e38f;
      ev.y = valid ? leaky(a4.y + ad4.y) : -3.0e38f;
      ev.z = valid ? leaky(a4.z + ad4.z) : -3.0e38f;
      ev.w = valid ? leaky(a4.w + ad4.w) : -3.0e38f;
      float4 mc = ev;
#pragma unroll
      for (int o = 1; o < 64; o <<= 1) {
        mc.x = fmaxf(mc.x, __shfl_xor(mc.x, o));
        mc.y = fmaxf(mc.y, __shfl_xor(mc.y, o));
        mc.z = fmaxf(mc.z, __shfl_xor(mc.z, o));
        mc.w = fmaxf(mc.w, __shfl_xor(mc.w, o));
      }
      float4 m2;
      m2.x = fmaxf(m.x, mc.x); m2.y = fmaxf(m.y, mc.y);
      m2.z = fmaxf(m.z, mc.z); m2.w = fmaxf(m.w, mc.w);
      float4 sc;
      sc.x = __expf(m.x - m2.x); sc.y = __expf(m.y - m2.y);
      sc.z = __expf(m.z - m2.z); sc.w = __expf(m.w - m2.w);
      const float msc = (h == 0) ? sc.x : (h == 1) ? sc.y : (h == 2) ? sc.z : sc.w;
      acc.x *= msc; acc.y *= msc; acc.z *= msc; acc.w *= msc;
      float4 w4;
      w4.x = valid ? __expf(ev.x - m2.x) : 0.f;
      w4.y = valid ? __expf(ev.y - m2.y) : 0.f;
      w4.z = valid ? __expf(ev.z - m2.z) : 0.f;
      w4.w = valid ? __expf(ev.w - m2.w) : 0.f;
      lsrc[wv][lane] = src << 8;
      *(float4*)&lw[wv][lane * 4] = w4;
      float4 ss = w4;
#pragma unroll
      for (int o = 1; o < 64; o <<= 1) {
        ss.x += __shfl_xor(ss.x, o);
        ss.y += __shfl_xor(ss.y, o);
        ss.z += __shfl_xor(ss.z, o);
        ss.w += __shfl_xor(ss.w, o);
      }
      s.x = s.x * sc.x + ss.x; s.y = s.y * sc.y + ss.y;
      s.z = s.z * sc.z + ss.z; s.w = s.w * sc.w + ss.w;
      m = m2;
      const int cd = min(64, deg - c0);
      const int cdr = (cd + 3) & ~3;
      for (int j = 0; j < cdr; j += 4) {
        const int o0 = lsrc[wv][j + 0], o1 = lsrc[wv][j + 1];
        const int o2 = lsrc[wv][j + 2], o3 = lsrc[wv][j + 3];
        const float w0 = lw[wv][(j + 0) * 4 + h];
        const float w1 = lw[wv][(j + 1) * 4 + h];
        const float w2 = lw[wv][(j + 2) * 4 + h];
        const float w3 = lw[wv][(j + 3) * 4 + h];
        const uint u0 = *(const uint*)(xw + o0 + ch);
        const uint u1 = *(const uint*)(xw + o1 + ch);
        const uint u2 = *(const uint*)(xw + o2 + ch);
        const uint u3 = *(const uint*)(xw + o3 + ch);
        const float4 x0 = fp8x4_to_f32(u0), x1 = fp8x4_to_f32(u1);
        const float4 x2 = fp8x4_to_f32(u2), x3 = fp8x4_to_f32(u3);
        acc.x += w0 * x0.x + w1 * x1.x + w2 * x2.x + w3 * x3.x;
        acc.y += w0 * x0.y + w1 * x1.y + w2 * x2.y + w3 * x3.y;
        acc.z += w0 * x0.z + w1 * x1.z + w2 * x2.z + w3 * x3.z;
        acc.w += w0 * x0.w + w1 * x1.w + w2 * x2.w + w3 * x3.w;
      }
    }
  }

  const float sh = (h == 0) ? s.x : (h == 1) ? s.y : (h == 2) ? s.z : s.w;
  const float inv = 1.f / (sh + 1e-16f);
  const float4 b4 = *(const float4*)(bias + ch);
  float o0 = acc.x * inv + b4.x, o1 = acc.y * inv + b4.y;
  float o2 = acc.z * inv + b4.z, o3 = acc.w * inv + b4.w;
  if (applyElu) {
    o0 = o0 > 0.f ? o0 : __expf(o0) - 1.f;
    o1 = o1 > 0.f ? o1 : __expf(o1) - 1.f;
    o2 = o2 > 0.f ? o2 : __expf(o2) - 1.f;
    o3 = o3 > 0.f ? o3 : __expf(o3) - 1.f;
  }
  ushort4 o4;
  o4.x = f2bf(o0); o4.y = f2bf(o1); o4.z = f2bf(o2); o4.w = f2bf(o3);
  *(ushort4*)(hout + (size_t)n * 256 + ch) = o4;
}

// xw40 padded to 64 cols (bf16); fast path for deg<=64, fused log_softmax.

__global__ __launch_bounds__(256) void aggregate40_lsm_kernel(
    const ushort* __restrict__ xw, const float* __restrict__ asB, const float* __restrict__ adB,
    const int* __restrict__ rowPtr, const int* __restrict__ colSrc,
    const float* __restrict__ bias, float* __restrict__ out) {
  __shared__ int   lsrc[4][64];   // element offsets (src*64)
  __shared__ float lw[4][64];
  const int n = (blockIdx.x * blockDim.x + threadIdx.x) >> 6;
  if (n >= NN) return;
  const int lane = threadIdx.x & 63;
  const int wv = (threadIdx.x >> 6) & 3;
  const bool act = lane < 40;
  const int p0 = rowPtr[n], deg = rowPtr[n + 1] - p0;
  const float adn = adB[n];
  const float es = leaky(asB[n] + adn);
  float m, s, acc;

  if (deg <= 64) {
    const bool valid = lane < deg;
    const int src = valid ? colSrc[p0 + lane] : n;
    float ev = valid ? leaky(asB[src] + adn) : -3.0e38f;
    float mc = ev;
#pragma unroll
    for (int o = 1; o < 64; o <<= 1) mc = fmaxf(mc, __shfl_xor(mc, o));
    m = fmaxf(es, mc);
    const float wv_ = valid ? __expf(ev - m) : 0.f;
    lsrc[wv][lane] = src << 6;
    lw[wv][lane] = wv_;
    float ss = wv_;
#pragma unroll
    for (int o = 1; o < 64; o <<= 1) ss += __shfl_xor(ss, o);
    const float wself = __expf(es - m);
    s = wself + ss;
    acc = wself * bf2f(xw[(size_t)n * 64 + lane]);
    const int cdr = (deg + 3) & ~3;
    for (int j = 0; j < cdr; j += 4) {
      const int o0 = lsrc[wv][j + 0], o1 = lsrc[wv][j + 1];
      const int o2 = lsrc[wv][j + 2], o3 = lsrc[wv][j + 3];
      const float w0 = lw[wv][j + 0], w1 = lw[wv][j + 1];
      const float w2 = lw[wv][j + 2], w3 = lw[wv][j + 3];
      const float x0 = bf2f(xw[o0 + lane]);
      const float x1 = bf2f(xw[o1 + lane]);
      const float x2 = bf2f(xw[o2 + lane]);
      const float x3 = bf2f(xw[o3 + lane]);
      acc += w0 * x0 + w1 * x1 + w2 * x2 + w3 * x3;
    }
  } else {
    m = es; s = 1.f;
    acc = bf2f(xw[(size_t)n * 64 + lane]);
    for (int c0 = 0; c0 < deg; c0 += 64) {
      const int e = c0 + lane;
      const bool valid = e < deg;
      const int src = valid ? colSrc[p0 + e] : n;
      float ev = valid ? leaky(asB[src] + adn) : -3.0e38f;
      float mc = ev;
#pragma unroll
      for (int o = 1; o < 64; o <<= 1) mc = fmaxf(mc, __shfl_xor(mc, o));
      const float m2 = fmaxf(m, mc);
      const float scl = __expf(m - m2);
      acc *= scl;
      float wv_ = valid ? __expf(ev - m2) : 0.f;
      lsrc[wv][lane] = src << 6;
      lw[wv][lane] = wv_;
      float ss = wv_;
#pragma unroll
      for (int o = 1; o < 64; o <<= 1) ss += __shfl_xor(ss, o);
      s = s * scl + ss;
      m = m2;
      const int cd = min(64, deg - c0);
      const int cdr = (cd + 3) & ~3;
      for (int j = 0; j < cdr; j += 4) {
        const int o0 = lsrc[wv][j + 0], o1 = lsrc[wv][j + 1];
        const int o2 = lsrc[wv][j + 2], o3 = lsrc[wv][j + 3];
        const float w0 = lw[wv][j + 0], w1 = lw[wv][j + 1];
        const float w2 = lw[wv][j + 2], w3 = lw[wv][j + 3];
        acc += w0 * bf2f(xw[o0 + lane]) + w1 * bf2f(xw[o1 + lane]) +
               w2 * bf2f(xw[o2 + lane]) + w3 * bf2f(xw[o3 + lane]);
      }
    }
  }

  float val = acc / (s + 1e-16f) + (act ? bias[lane] : 0.f);
  float v = act ? val : -1e30f;
  float mx = v;
#pragma unroll
  for (int o = 1; o < 64; o <<= 1) mx = fmaxf(mx, __shfl_xor(mx, o));
  float ex = act ? __expf(val - mx) : 0.f;
#pragma unroll
  for (int o = 1; o < 64; o <<= 1) ex += __shfl_xor(ex, o);
  if (act) out[(size_t)n * 40 + lane] = val - mx - __logf(ex);
}

// ---------------- launch ----------------

extern "C" void kernel_launch(void* const* d_in, const int* in_sizes, int n_in,
                              void* d_out, int out_size, void* d_ws, size_t ws_size,
                              hipStream_t stream) {
  const float* x   = (const float*)d_in[0];
  const int*   ei  = (const int*)d_in[1];
  const float* W1  = (const float*)d_in[2];
  const float* a1s = (const float*)d_in[3];
  const float* a1d = (const float*)d_in[4];
  const float* b1  = (const float*)d_in[5];
  const float* W2  = (const float*)d_in[6];
  const float* a2s = (const float*)d_in[7];
  const float* a2d = (const float*)d_in[8];
  const float* b2  = (const float*)d_in[9];
  const float* W3  = (const float*)d_in[10];
  const float* a3s = (const float*)d_in[11];
  const float* a3d = (const float*)d_in[12];
  const float* b3  = (const float*)d_in[13];
  float* out = (float*)d_out;

  char* w = (char*)d_ws;
  unsigned char* xwBuf = (unsigned char*)w;  w += (size_t)NN * 256;   // fp8 messages
  ushort* hBuf  = (ushort*)w;  w += (size_t)NN * 256 * 2;             // agg out (bf16)
  ushort* xw40  = (ushort*)w;  w += (size_t)NN * 64 * 2;
  float* asBuf  = (float*)w;   w += (size_t)NN * 4 * 4;
  float* adBuf  = (float*)w;   w += (size_t)NN * 4 * 4;
  ushort* Bf1   = (ushort*)w;  w += (size_t)T1 * 2;
  ushort* Bf2   = (ushort*)w;  w += (size_t)T2 * 2;
  ushort* Bf3   = (ushort*)w;  w += (size_t)T3 * 2;
  int* counts   = (int*)w;     w += (size_t)NN * 4;
  int* cursor   = (int*)w;     w += (size_t)NN * 4;
  int* rowPtr   = (int*)w;     w += (size_t)(NN + 1) * 4;
  int* colSrc   = (int*)w;     w += (size_t)NE * 4;
  int* partial  = (int*)w;     w += (size_t)NN * 4;
  int* blockSums = (int*)w;    w += 64 * 4;

  const int nScanBlocks = (NN + 1023) / 1024;  // 49

  // CSR build
  hipMemsetAsync(counts, 0, (size_t)2 * NN * 4, stream);
  hist_kernel<<<(NE + 255) / 256, 256, 0, stream>>>(ei + NE, counts);
  scan1_kernel<<<nScanBlocks, 1024, 0, stream>>>(counts, partial, blockSums);
  scan23_kernel<<<(NN + 255) / 256, 256, 0, stream>>>(partial, blockSums, rowPtr);
  fill_kernel<<<(NE + 255) / 256, 256, 0, stream>>>(ei, ei + NE, rowPtr, cursor, colSrc);

  // pre-fragment all weights (+ fused logit columns)
  prefrag_all_kernel<<<(T1 + T2 + T3 + 255) / 256, 256, 0, stream>>>(
      W1, a1s, a1d, W2, a2s, a2d, W3, a3s, a3d, Bf1, Bf2, Bf3);

  const int gemmBlocks = (NN + 127) / 128;  // 391 row-blocks (128 rows, 8 waves)
  const dim3 gemmGrid(gemmBlocks, 2);       // x: rows, y: column group
  const int nodeBlocks = NN / 4;            // wave per node

  // layer 1: 128 -> 4x64 (fp32 A on the fly; fp8 message out). 17 tiles: 9+9, STEP=8.
  gemm_mfma_kernel<9, 8, 4, true, true><<<gemmGrid, 512, 0, stream>>>(x, Bf1, xwBuf, asBuf, adBuf, 256, 4);
  aggregate256_kernel<<<nodeBlocks, 256, 0, stream>>>(xwBuf, asBuf, adBuf, rowPtr, colSrc, b1, hBuf, 1);

  // layer 2: 256 -> 4x64 (fp8 message out)
  gemm_mfma_kernel<9, 8, 8, false, true><<<gemmGrid, 512, 0, stream>>>(hBuf, Bf2, xwBuf, asBuf, adBuf, 256, 4);
  aggregate256_kernel<<<nodeBlocks, 256, 0, stream>>>(xwBuf, asBuf, adBuf, rowPtr, colSrc, b2, hBuf, 1);

  // layer 3: 256 -> 40 (padded to 64, bf16) + log_softmax. 5 tiles: 3+3, STEP=2.
  gemm_mfma_kernel<3, 2, 8, false, false><<<gemmGrid, 512, 0, stream>>>(hBuf, Bf3, xw40, asBuf, adBuf, 64, 1);
  aggregate40_lsm_kernel<<<nodeBlocks, 256, 0, stream>>>(xw40, asBuf, adBuf, rowPtr, colSrc, b3, out);
}

// Round 12
// 355.300 us; speedup vs baseline: 1.0473x; 1.0473x over previous
//
#include <hip/hip_runtime.h>
#include <hip/hip_bf16.h>

#define NN 50000
#define NE 800000

using bf16x8 = __attribute__((ext_vector_type(8))) short;
using f32x4  = __attribute__((ext_vector_type(4))) float;
using f32x2  = __attribute__((ext_vector_type(2))) float;

__device__ __forceinline__ ushort f2bf(float f) {
  uint x = __float_as_uint(f);
  return (ushort)((x + 0x7FFFu + ((x >> 16) & 1u)) >> 16);
}
__device__ __forceinline__ float bf2f(ushort u) {
  return __uint_as_float(((uint)u) << 16);
}
__device__ __forceinline__ float leaky(float x) { return fmaxf(x, 0.2f * x); }

// fp8 e4m3 (OCP) helpers — HW packed converts
__device__ __forceinline__ unsigned char f32_to_fp8(float v) {
  int pk = __builtin_amdgcn_cvt_pk_fp8_f32(v, v, 0, false);
  return (unsigned char)(pk & 0xff);
}
__device__ __forceinline__ float4 fp8x4_to_f32(uint u) {
  f32x2 lo = __builtin_amdgcn_cvt_pk_f32_fp8((int)u, false);
  f32x2 hi = __builtin_amdgcn_cvt_pk_f32_fp8((int)u, true);
  return make_float4(lo[0], lo[1], hi[0], hi[1]);
}

// async global->LDS, 16B per lane
__device__ __forceinline__ void gload_lds16(const void* g, void* l) {
  __builtin_amdgcn_global_load_lds(
      (const __attribute__((address_space(1))) unsigned int*)g,
      (__attribute__((address_space(3))) unsigned int*)l, 16, 0, 0);
}

// ---------------- CSR scans ----------------

__global__ __launch_bounds__(1024) void scan1_kernel(const int* __restrict__ counts,
                                                     int* __restrict__ partial,
                                                     int* __restrict__ blockSums) {
  __shared__ int sm[1024];
  int i = blockIdx.x * 1024 + threadIdx.x;
  sm[threadIdx.x] = (i < NN) ? counts[i] : 0;
  __syncthreads();
  for (int off = 1; off < 1024; off <<= 1) {
    int t = (threadIdx.x >= off) ? sm[threadIdx.x - off] : 0;
    __syncthreads();
    sm[threadIdx.x] += t;
    __syncthreads();
  }
  if (i < NN) partial[i] = sm[threadIdx.x];
  if (threadIdx.x == 1023) blockSums[blockIdx.x] = sm[1023];
}

__global__ __launch_bounds__(256) void scan23_kernel(const int* __restrict__ partial,
                                                     const int* __restrict__ blockSums,
                                                     int* __restrict__ rowPtr) {
  int i = blockIdx.x * 256 + threadIdx.x;
  if (i < NN) {
    const int nb = i >> 10;
    int off = 0;
    for (int b = 0; b < nb; ++b) off += blockSums[b];
    rowPtr[i + 1] = partial[i] + off;
    if (i == 0) rowPtr[0] = 0;
  }
}

// ---------------- pre-fragment B' = [W | pad | W@att_s | W@att_d | pad] into MFMA lane order ----

__device__ __forceinline__ void prefrag_one(int idx, const float* __restrict__ W,
                                            const float* __restrict__ atS,
                                            const float* __restrict__ atD,
                                            ushort* __restrict__ Bf,
                                            int Mout, int Mpad, int nh, int Cdim, int KC) {
  const int i = idx & 7;
  const int lane = (idx >> 3) & 63;
  const int kc = (idx >> 9) % KC;
  const int ct = idx / (KC * 512);
  const int k = kc * 32 + (lane >> 4) * 8 + i;
  const int col = ct * 16 + (lane & 15);
  float v = 0.f;
  if (col < Mout) {
    v = W[(size_t)k * Mout + col];
  } else if (col >= Mpad && col < Mpad + nh) {
    const int h = col - Mpad; float s = 0.f;
    for (int c = 0; c < Cdim; ++c) s += W[(size_t)k * Mout + h * Cdim + c] * atS[h * Cdim + c];
    v = s;
  } else if (col >= Mpad + nh && col < Mpad + 2 * nh) {
    const int h = col - Mpad - nh; float s = 0.f;
    for (int c = 0; c < Cdim; ++c) s += W[(size_t)k * Mout + h * Cdim + c] * atD[h * Cdim + c];
    v = s;
  }
  Bf[idx] = f2bf(v);
}

#define T1 (17 * 4 * 512)
#define T2 (17 * 8 * 512)
#define T3 (5 * 8 * 512)
#define PRE_BLOCKS ((T1 + T2 + T3 + 511) / 512)   // 244
#define EDGE_BLOCKS ((NE + 511) / 512)            // 1563

// fused: prefrag (blocks 0..243) + hist (blocks 244..)
__global__ __launch_bounds__(512) void prefrag_hist_kernel(
    const float* __restrict__ W1, const float* __restrict__ a1s, const float* __restrict__ a1d,
    const float* __restrict__ W2, const float* __restrict__ a2s, const float* __restrict__ a2d,
    const float* __restrict__ W3, const float* __restrict__ a3s, const float* __restrict__ a3d,
    ushort* __restrict__ Bf1, ushort* __restrict__ Bf2, ushort* __restrict__ Bf3,
    const int* __restrict__ dst, int* __restrict__ counts) {
  if (blockIdx.x < PRE_BLOCKS) {
    int idx = blockIdx.x * 512 + threadIdx.x;
    if (idx < T1) {
      prefrag_one(idx, W1, a1s, a1d, Bf1, 256, 256, 4, 64, 4);
    } else if (idx < T1 + T2) {
      prefrag_one(idx - T1, W2, a2s, a2d, Bf2, 256, 256, 4, 64, 8);
    } else if (idx < T1 + T2 + T3) {
      prefrag_one(idx - T1 - T2, W3, a3s, a3d, Bf3, 40, 64, 1, 40, 8);
    }
  } else {
    int e = (blockIdx.x - PRE_BLOCKS) * 512 + threadIdx.x;
    if (e < NE) atomicAdd(&counts[dst[e]], 1);
  }
}

// ---------------- bf16 MFMA GEMM body: 128-row blocks (8 waves), LDS dbuf B (r10 config) ----

template <int NCT, int KC, bool AF32, bool OUT8>
__device__ __forceinline__ void gemm_body(int bid, const void* __restrict__ Araw,
                                          const ushort* __restrict__ Bf,
                                          void* __restrict__ xwOut,
                                          float* __restrict__ asB,
                                          float* __restrict__ adB,
                                          int Mpad, int nh) {
  __shared__ __align__(16) ushort sB[2][NCT * 512];
  constexpr int K = KC * 32;
  const int lane = threadIdx.x & 63;
  const int w = threadIdx.x >> 6;         // 8 waves
  const int rowBase = bid * 128 + w * 16;
  const int arow = min(rowBase + (lane & 15), NN - 1);   // clamp; no early return (barriers!)
  const int koff = (lane >> 4) * 8;
  f32x4 acc[NCT];
#pragma unroll
  for (int ct = 0; ct < NCT; ++ct) acc[ct] = (f32x4){0.f, 0.f, 0.f, 0.f};

#pragma unroll
  for (int ct0 = 0; ct0 < NCT; ++ct0) {
    if ((ct0 & 7) == w)
      gload_lds16(Bf + (((size_t)ct0 * KC) << 9) + lane * 8, &sB[0][ct0 * 512]);
  }
  __syncthreads();

#pragma unroll
  for (int kc = 0; kc < KC; ++kc) {
    const int nb = kc & 1;
    if (kc + 1 < KC) {
#pragma unroll
      for (int ct0 = 0; ct0 < NCT; ++ct0) {
        if ((ct0 & 7) == w)
          gload_lds16(Bf + (((size_t)ct0 * KC + kc + 1) << 9) + lane * 8,
                      &sB[nb ^ 1][ct0 * 512]);
      }
    }
    bf16x8 af;
    if constexpr (AF32) {
      const float* ap = (const float*)Araw + (size_t)arow * K + koff + kc * 32;
      float4 p0 = *(const float4*)ap;
      float4 p1 = *(const float4*)(ap + 4);
      af[0] = (short)f2bf(p0.x); af[1] = (short)f2bf(p0.y);
      af[2] = (short)f2bf(p0.z); af[3] = (short)f2bf(p0.w);
      af[4] = (short)f2bf(p1.x); af[5] = (short)f2bf(p1.y);
      af[6] = (short)f2bf(p1.z); af[7] = (short)f2bf(p1.w);
    } else {
      const ushort* ap = (const ushort*)Araw + (size_t)arow * K + koff + kc * 32;
      af = *reinterpret_cast<const bf16x8*>(ap);
    }
#pragma unroll
    for (int ct = 0; ct < NCT; ++ct) {
      bf16x8 bfr = *reinterpret_cast<const bf16x8*>(&sB[nb][ct * 512 + lane * 8]);
      acc[ct] = __builtin_amdgcn_mfma_f32_16x16x32_bf16(af, bfr, acc[ct], 0, 0, 0);
    }
    __syncthreads();   // drains vmcnt (prefetch DMA) + orders buffer reuse
  }

  const int colL = lane & 15;
  const int rquad = (lane >> 4) * 4;
#pragma unroll
  for (int ct = 0; ct < NCT; ++ct) {
    const int col = ct * 16 + colL;
#pragma unroll
    for (int r = 0; r < 4; ++r) {
      const int row = rowBase + rquad + r;
      if (row < NN) {
        const float v = acc[ct][r];
        if (col < Mpad) {
          if constexpr (OUT8) {
            ((unsigned char*)xwOut)[(size_t)row * Mpad + col] = f32_to_fp8(v);
          } else {
            ((ushort*)xwOut)[(size_t)row * Mpad + col] = f2bf(v);
          }
        } else if (col < Mpad + nh) {
          asB[(size_t)row * nh + (col - Mpad)] = v;
        } else if (col < Mpad + 2 * nh) {
          adB[(size_t)row * nh + (col - Mpad - nh)] = v;
        }
      }
    }
  }
}

template <int NCT, int KC, bool AF32, bool OUT8>
__global__ __launch_bounds__(512) void gemm_kernel(const void* __restrict__ Araw,
                                                   const ushort* __restrict__ Bf,
                                                   void* __restrict__ xwOut,
                                                   float* __restrict__ asB,
                                                   float* __restrict__ adB,
                                                   int Mpad, int nh) {
  gemm_body<NCT, KC, AF32, OUT8>(blockIdx.x, Araw, Bf, xwOut, asB, adB, Mpad, nh);
}

#define GEMM_BLOCKS ((NN + 127) / 128)   // 391

// fused: gemm1 (blocks 0..390) + CSR fill (blocks 391..)
__global__ __launch_bounds__(512) void gemm1_fill_kernel(
    const float* __restrict__ x, const ushort* __restrict__ Bf1,
    unsigned char* __restrict__ xwOut, float* __restrict__ asB, float* __restrict__ adB,
    const int* __restrict__ srcArr, const int* __restrict__ dstArr,
    const int* __restrict__ rowPtr, int* __restrict__ cursor, int* __restrict__ colSrc) {
  if (blockIdx.x < GEMM_BLOCKS) {
    gemm_body<17, 4, true, true>(blockIdx.x, x, Bf1, xwOut, asB, adB, 256, 4);
  } else {
    int e = (blockIdx.x - GEMM_BLOCKS) * 512 + threadIdx.x;
    if (e < NE) {
      int d = dstArr[e];
      int p = rowPtr[d] + atomicAdd(&cursor[d], 1);
      colSrc[p] = srcArr[e];
    }
  }
}

// ---------------- aggregation: wave/node; fast single-pass softmax for deg<=64 ----------------

__global__ __launch_bounds__(256) void aggregate256_kernel(
    const unsigned char* __restrict__ xw, const float* __restrict__ asB,
    const float* __restrict__ adB,
    const int* __restrict__ rowPtr, const int* __restrict__ colSrc,
    const float* __restrict__ bias, ushort* __restrict__ hout, int applyElu) {
  __shared__ int   lsrc[4][64];    // row byte offsets (src*256)
  __shared__ float lw[4][256];
  const int n = (blockIdx.x * blockDim.x + threadIdx.x) >> 6;
  if (n >= NN) return;
  const int lane = threadIdx.x & 63;
  const int wv = (threadIdx.x >> 6) & 3;
  const int h = lane >> 4;
  const int ch = lane * 4;
  const int p0 = rowPtr[n], deg = rowPtr[n + 1] - p0;
  const float4 ad4 = *(const float4*)(adB + n * 4);
  const float4 as4 = *(const float4*)(asB + n * 4);
  float4 es;  // self-loop logit per head
  es.x = leaky(as4.x + ad4.x); es.y = leaky(as4.y + ad4.y);
  es.z = leaky(as4.z + ad4.z); es.w = leaky(as4.w + ad4.w);
  float4 s, acc;
  float4 m;

  if (deg <= 64) {
    // ---- fast path: one chunk, single-pass softmax ----
    const bool valid = lane < deg;
    const int src = valid ? colSrc[p0 + lane] : n;
    const float4 a4 = *(const float4*)(asB + src * 4);
    float4 ev;
    ev.x = valid ? leaky(a4.x + ad4.x) : -3.0e38f;
    ev.y = valid ? leaky(a4.y + ad4.y) : -3.0e38f;
    ev.z = valid ? leaky(a4.z + ad4.z) : -3.0e38f;
    ev.w = valid ? leaky(a4.w + ad4.w) : -3.0e38f;
    float4 mc = ev;
#pragma unroll
    for (int o = 1; o < 64; o <<= 1) {
      mc.x = fmaxf(mc.x, __shfl_xor(mc.x, o));
      mc.y = fmaxf(mc.y, __shfl_xor(mc.y, o));
      mc.z = fmaxf(mc.z, __shfl_xor(mc.z, o));
      mc.w = fmaxf(mc.w, __shfl_xor(mc.w, o));
    }
    m.x = fmaxf(es.x, mc.x); m.y = fmaxf(es.y, mc.y);
    m.z = fmaxf(es.z, mc.z); m.w = fmaxf(es.w, mc.w);
    float4 w4;
    w4.x = valid ? __expf(ev.x - m.x) : 0.f;
    w4.y = valid ? __expf(ev.y - m.y) : 0.f;
    w4.z = valid ? __expf(ev.z - m.z) : 0.f;
    w4.w = valid ? __expf(ev.w - m.w) : 0.f;
    lsrc[wv][lane] = src << 8;
    *(float4*)&lw[wv][lane * 4] = w4;
    float4 ss = w4;
#pragma unroll
    for (int o = 1; o < 64; o <<= 1) {
      ss.x += __shfl_xor(ss.x, o);
      ss.y += __shfl_xor(ss.y, o);
      ss.z += __shfl_xor(ss.z, o);
      ss.w += __shfl_xor(ss.w, o);
    }
    float4 wself;
    wself.x = __expf(es.x - m.x); wself.y = __expf(es.y - m.y);
    wself.z = __expf(es.z - m.z); wself.w = __expf(es.w - m.w);
    s.x = wself.x + ss.x; s.y = wself.y + ss.y;
    s.z = wself.z + ss.z; s.w = wself.w + ss.w;
    const float wsh = (h == 0) ? wself.x : (h == 1) ? wself.y : (h == 2) ? wself.z : wself.w;
    const float4 x4 = fp8x4_to_f32(*(const uint*)(xw + (size_t)n * 256 + ch));
    acc = make_float4(wsh * x4.x, wsh * x4.y, wsh * x4.z, wsh * x4.w);
    // weighted gather, unroll 4 (round up to 4; dummies have w=0)
    const int cdr = (deg + 3) & ~3;
    for (int j = 0; j < cdr; j += 4) {
      const int o0 = lsrc[wv][j + 0], o1 = lsrc[wv][j + 1];
      const int o2 = lsrc[wv][j + 2], o3 = lsrc[wv][j + 3];
      const float w0 = lw[wv][(j + 0) * 4 + h];
      const float w1 = lw[wv][(j + 1) * 4 + h];
      const float w2 = lw[wv][(j + 2) * 4 + h];
      const float w3 = lw[wv][(j + 3) * 4 + h];
      const uint u0 = *(const uint*)(xw + o0 + ch);
      const uint u1 = *(const uint*)(xw + o1 + ch);
      const uint u2 = *(const uint*)(xw + o2 + ch);
      const uint u3 = *(const uint*)(xw + o3 + ch);
      const float4 x0 = fp8x4_to_f32(u0), x1 = fp8x4_to_f32(u1);
      const float4 x2 = fp8x4_to_f32(u2), x3 = fp8x4_to_f32(u3);
      acc.x += w0 * x0.x + w1 * x1.x + w2 * x2.x + w3 * x3.x;
      acc.y += w0 * x0.y + w1 * x1.y + w2 * x2.y + w3 * x3.y;
      acc.z += w0 * x0.z + w1 * x1.z + w2 * x2.z + w3 * x3.z;
      acc.w += w0 * x0.w + w1 * x1.w + w2 * x2.w + w3 * x3.w;
    }
  } else {
    // ---- general path: online-softmax chunks ----
    m = es;
    s = make_float4(1.f, 1.f, 1.f, 1.f);
    const float4 x4 = fp8x4_to_f32(*(const uint*)(xw + (size_t)n * 256 + ch));
    acc = make_float4(x4.x, x4.y, x4.z, x4.w);
    for (int c0 = 0; c0 < deg; c0 += 64) {
      const int e = c0 + lane;
      const bool valid = e < deg;
      const int src = valid ? colSrc[p0 + e] : n;
      const float4 a4 = *(const float4*)(asB + src * 4);
      float4 ev;
      ev.x = valid ? leaky(a4.x + ad4.x) : -3.0e38f;
      ev.y = valid ? leaky(a4.y + ad4.y) : -3.0e38f;
      ev.z = valid ? leaky(a4.z + ad4.z) : -3.0e38f;
      ev.w = valid ? leaky(a4.w + ad4.w) : -3.0e38f;
      float4 mc = ev;
#pragma unroll
      for (int o = 1; o < 64; o <<= 1) {
        mc.x = fmaxf(mc.x, __shfl_xor(mc.x, o));
        mc.y = fmaxf(mc.y, __shfl_xor(mc.y, o));
        mc.z = fmaxf(mc.z, __shfl_xor(mc.z, o));
        mc.w = fmaxf(mc.w, __shfl_xor(mc.w, o));
      }
      float4 m2;
      m2.x = fmaxf(m.x, mc.x); m2.y = fmaxf(m.y, mc.y);
      m2.z = fmaxf(m.z, mc.z); m2.w = fmaxf(m.w, mc.w);
      float4 sc;
      sc.x = __expf(m.x - m2.x); sc.y = __expf(m.y - m2.y);
      sc.z = __expf(m.z - m2.z); sc.w = __expf(m.w - m2.w);
      const float msc = (h == 0) ? sc.x : (h == 1) ? sc.y : (h == 2) ? sc.z : sc.w;
      acc.x *= msc; acc.y *= msc; acc.z *= msc; acc.w *= msc;
      float4 w4;
      w4.x = valid ? __expf(ev.x - m2.x) : 0.f;
      w4.y = valid ? __expf(ev.y - m2.y) : 0.f;
      w4.z = valid ? __expf(ev.z - m2.z) : 0.f;
      w4.w = valid ? __expf(ev.w - m2.w) : 0.f;
      lsrc[wv][lane] = src << 8;
      *(float4*)&lw[wv][lane * 4] = w4;
      float4 ss = w4;
#pragma unroll
      for (int o = 1; o < 64; o <<= 1) {
        ss.x += __shfl_xor(ss.x, o);
        ss.y += __shfl_xor(ss.y, o);
        ss.z += __shfl_xor(ss.z, o);
        ss.w += __shfl_xor(ss.w, o);
      }
      s.x = s.x * sc.x + ss.x; s.y = s.y * sc.y + ss.y;
      s.z = s.z * sc.z + ss.z; s.w = s.w * sc.w + ss.w;
      m = m2;
      const int cd = min(64, deg - c0);
      const int cdr = (cd + 3) & ~3;
      for (int j = 0; j < cdr; j += 4) {
        const int o0 = lsrc[wv][j + 0], o1 = lsrc[wv][j + 1];
        const int o2 = lsrc[wv][j + 2], o3 = lsrc[wv][j + 3];
        const float w0 = lw[wv][(j + 0) * 4 + h];
        const float w1 = lw[wv][(j + 1) * 4 + h];
        const float w2 = lw[wv][(j + 2) * 4 + h];
        const float w3 = lw[wv][(j + 3) * 4 + h];
        const uint u0 = *(const uint*)(xw + o0 + ch);
        const uint u1 = *(const uint*)(xw + o1 + ch);
        const uint u2 = *(const uint*)(xw + o2 + ch);
        const uint u3 = *(const uint*)(xw + o3 + ch);
        const float4 x0 = fp8x4_to_f32(u0), x1 = fp8x4_to_f32(u1);
        const float4 x2 = fp8x4_to_f32(u2), x3 = fp8x4_to_f32(u3);
        acc.x += w0 * x0.x + w1 * x1.x + w2 * x2.x + w3 * x3.x;
        acc.y += w0 * x0.y + w1 * x1.y + w2 * x2.y + w3 * x3.y;
        acc.z += w0 * x0.z + w1 * x1.z + w2 * x2.z + w3 * x3.z;
        acc.w += w0 * x0.w + w1 * x1.w + w2 * x2.w + w3 * x3.w;
      }
    }
  }

  const float sh = (h == 0) ? s.x : (h == 1) ? s.y : (h == 2) ? s.z : s.w;
  const float inv = 1.f / (sh + 1e-16f);
  const float4 b4 = *(const float4*)(bias + ch);
  float o0 = acc.x * inv + b4.x, o1 = acc.y * inv + b4.y;
  float o2 = acc.z * inv + b4.z, o3 = acc.w * inv + b4.w;
  if (applyElu) {
    o0 = o0 > 0.f ? o0 : __expf(o0) - 1.f;
    o1 = o1 > 0.f ? o1 : __expf(o1) - 1.f;
    o2 = o2 > 0.f ? o2 : __expf(o2) - 1.f;
    o3 = o3 > 0.f ? o3 : __expf(o3) - 1.f;
  }
  ushort4 o4;
  o4.x = f2bf(o0); o4.y = f2bf(o1); o4.z = f2bf(o2); o4.w = f2bf(o3);
  *(ushort4*)(hout + (size_t)n * 256 + ch) = o4;
}

// xw40 padded to 64 cols (bf16); fast path for deg<=64, fused log_softmax.

__global__ __launch_bounds__(256) void aggregate40_lsm_kernel(
    const ushort* __restrict__ xw, const float* __restrict__ asB, const float* __restrict__ adB,
    const int* __restrict__ rowPtr, const int* __restrict__ colSrc,
    const float* __restrict__ bias, float* __restrict__ out) {
  __shared__ int   lsrc[4][64];   // element offsets (src*64)
  __shared__ float lw[4][64];
  const int n = (blockIdx.x * blockDim.x + threadIdx.x) >> 6;
  if (n >= NN) return;
  const int lane = threadIdx.x & 63;
  const int wv = (threadIdx.x >> 6) & 3;
  const bool act = lane < 40;
  const int p0 = rowPtr[n], deg = rowPtr[n + 1] - p0;
  const float adn = adB[n];
  const float es = leaky(asB[n] + adn);
  float m, s, acc;

  if (deg <= 64) {
    const bool valid = lane < deg;
    const int src = valid ? colSrc[p0 + lane] : n;
    float ev = valid ? leaky(asB[src] + adn) : -3.0e38f;
    float mc = ev;
#pragma unroll
    for (int o = 1; o < 64; o <<= 1) mc = fmaxf(mc, __shfl_xor(mc, o));
    m = fmaxf(es, mc);
    const float wv_ = valid ? __expf(ev - m) : 0.f;
    lsrc[wv][lane] = src << 6;
    lw[wv][lane] = wv_;
    float ss = wv_;
#pragma unroll
    for (int o = 1; o < 64; o <<= 1) ss += __shfl_xor(ss, o);
    const float wself = __expf(es - m);
    s = wself + ss;
    acc = wself * bf2f(xw[(size_t)n * 64 + lane]);
    const int cdr = (deg + 3) & ~3;
    for (int j = 0; j < cdr; j += 4) {
      const int o0 = lsrc[wv][j + 0], o1 = lsrc[wv][j + 1];
      const int o2 = lsrc[wv][j + 2], o3 = lsrc[wv][j + 3];
      const float w0 = lw[wv][j + 0], w1 = lw[wv][j + 1];
      const float w2 = lw[wv][j + 2], w3 = lw[wv][j + 3];
      const float x0 = bf2f(xw[o0 + lane]);
      const float x1 = bf2f(xw[o1 + lane]);
      const float x2 = bf2f(xw[o2 + lane]);
      const float x3 = bf2f(xw[o3 + lane]);
      acc += w0 * x0 + w1 * x1 + w2 * x2 + w3 * x3;
    }
  } else {
    m = es; s = 1.f;
    acc = bf2f(xw[(size_t)n * 64 + lane]);
    for (int c0 = 0; c0 < deg; c0 += 64) {
      const int e = c0 + lane;
      const bool valid = e < deg;
      const int src = valid ? colSrc[p0 + e] : n;
      float ev = valid ? leaky(asB[src] + adn) : -3.0e38f;
      float mc = ev;
#pragma unroll
      for (int o = 1; o < 64; o <<= 1) mc = fmaxf(mc, __shfl_xor(mc, o));
      const float m2 = fmaxf(m, mc);
      const float scl = __expf(m - m2);
      acc *= scl;
      float wv_ = valid ? __expf(ev - m2) : 0.f;
      lsrc[wv][lane] = src << 6;
      lw[wv][lane] = wv_;
      float ss = wv_;
#pragma unroll
      for (int o = 1; o < 64; o <<= 1) ss += __shfl_xor(ss, o);
      s = s * scl + ss;
      m = m2;
      const int cd = min(64, deg - c0);
      const int cdr = (cd + 3) & ~3;
      for (int j = 0; j < cdr; j += 4) {
        const int o0 = lsrc[wv][j + 0], o1 = lsrc[wv][j + 1];
        const int o2 = lsrc[wv][j + 2], o3 = lsrc[wv][j + 3];
        const float w0 = lw[wv][j + 0], w1 = lw[wv][j + 1];
        const float w2 = lw[wv][j + 2], w3 = lw[wv][j + 3];
        acc += w0 * bf2f(xw[o0 + lane]) + w1 * bf2f(xw[o1 + lane]) +
               w2 * bf2f(xw[o2 + lane]) + w3 * bf2f(xw[o3 + lane]);
      }
    }
  }

  float val = acc / (s + 1e-16f) + (act ? bias[lane] : 0.f);
  float v = act ? val : -1e30f;
  float mx = v;
#pragma unroll
  for (int o = 1; o < 64; o <<= 1) mx = fmaxf(mx, __shfl_xor(mx, o));
  float ex = act ? __expf(val - mx) : 0.f;
#pragma unroll
  for (int o = 1; o < 64; o <<= 1) ex += __shfl_xor(ex, o);
  if (act) out[(size_t)n * 40 + lane] = val - mx - __logf(ex);
}

// ---------------- launch ----------------

extern "C" void kernel_launch(void* const* d_in, const int* in_sizes, int n_in,
                              void* d_out, int out_size, void* d_ws, size_t ws_size,
                              hipStream_t stream) {
  const float* x   = (const float*)d_in[0];
  const int*   ei  = (const int*)d_in[1];
  const float* W1  = (const float*)d_in[2];
  const float* a1s = (const float*)d_in[3];
  const float* a1d = (const float*)d_in[4];
  const float* b1  = (const float*)d_in[5];
  const float* W2  = (const float*)d_in[6];
  const float* a2s = (const float*)d_in[7];
  const float* a2d = (const float*)d_in[8];
  const float* b2  = (const float*)d_in[9];
  const float* W3  = (const float*)d_in[10];
  const float* a3s = (const float*)d_in[11];
  const float* a3d = (const float*)d_in[12];
  const float* b3  = (const float*)d_in[13];
  float* out = (float*)d_out;

  char* w = (char*)d_ws;
  unsigned char* xwBuf = (unsigned char*)w;  w += (size_t)NN * 256;   // fp8 messages
  ushort* hBuf  = (ushort*)w;  w += (size_t)NN * 256 * 2;             // agg out (bf16)
  ushort* xw40  = (ushort*)w;  w += (size_t)NN * 64 * 2;
  float* asBuf  = (float*)w;   w += (size_t)NN * 4 * 4;
  float* adBuf  = (float*)w;   w += (size_t)NN * 4 * 4;
  ushort* Bf1   = (ushort*)w;  w += (size_t)T1 * 2;
  ushort* Bf2   = (ushort*)w;  w += (size_t)T2 * 2;
  ushort* Bf3   = (ushort*)w;  w += (size_t)T3 * 2;
  int* counts   = (int*)w;     w += (size_t)NN * 4;
  int* cursor   = (int*)w;     w += (size_t)NN * 4;
  int* rowPtr   = (int*)w;     w += (size_t)(NN + 1) * 4;
  int* colSrc   = (int*)w;     w += (size_t)NE * 4;
  int* partial  = (int*)w;     w += (size_t)NN * 4;
  int* blockSums = (int*)w;    w += 64 * 4;

  const int nScanBlocks = (NN + 1023) / 1024;  // 49

  // counts & cursor zeroed in one memset (adjacent)
  hipMemsetAsync(counts, 0, (size_t)2 * NN * 4, stream);

  // fused: prefrag (Bf1/2/3) + hist (counts)
  prefrag_hist_kernel<<<PRE_BLOCKS + EDGE_BLOCKS, 512, 0, stream>>>(
      W1, a1s, a1d, W2, a2s, a2d, W3, a3s, a3d, Bf1, Bf2, Bf3, ei + NE, counts);

  scan1_kernel<<<nScanBlocks, 1024, 0, stream>>>(counts, partial, blockSums);
  scan23_kernel<<<(NN + 255) / 256, 256, 0, stream>>>(partial, blockSums, rowPtr);

  const int nodeBlocks = NN / 4;  // wave per node

  // fused: layer-1 GEMM (needs Bf1) + CSR fill (needs rowPtr) — independent writes
  gemm1_fill_kernel<<<GEMM_BLOCKS + EDGE_BLOCKS, 512, 0, stream>>>(
      x, Bf1, xwBuf, asBuf, adBuf, ei, ei + NE, rowPtr, cursor, colSrc);

  aggregate256_kernel<<<nodeBlocks, 256, 0, stream>>>(xwBuf, asBuf, adBuf, rowPtr, colSrc, b1, hBuf, 1);

  // layer 2: 256 -> 4x64 (fp8 message out)
  gemm_kernel<17, 8, false, true><<<GEMM_BLOCKS, 512, 0, stream>>>(hBuf, Bf2, xwBuf, asBuf, adBuf, 256, 4);
  aggregate256_kernel<<<nodeBlocks, 256, 0, stream>>>(xwBuf, asBuf, adBuf, rowPtr, colSrc, b2, hBuf, 1);

  // layer 3: 256 -> 40 (padded to 64, bf16) + log_softmax
  gemm_kernel<5, 8, false, false><<<GEMM_BLOCKS, 512, 0, stream>>>(hBuf, Bf3, xw40, asBuf, adBuf, 64, 1);
  aggregate40_lsm_kernel<<<nodeBlocks, 256, 0, stream>>>(xw40, asBuf, adBuf, rowPtr, colSrc, b3, out);
}